// Round 3
// baseline (177.908 us; speedup 1.0000x reference)
//
#include <hip/hip_runtime.h>
#include <math.h>

#define CLASSES 8
#define SIZE 512
#define ISZ 512
#define CSZ 512
#define BATCH 64
#define CMS 4
#define NBUCKET 16
#define LR 0.01f
#define WCLIP 5.0f

// ---------------- pre-pass: packed layouts in d_ws ----------------
// Lt    (B, C*I)      : Lt[b*4096 + ci]                  = logits[ci, b]
// Lpk   (C*I/4, B, 4) : Lpk[(ci>>2)*256 + 4*b + (ci&3)]  = logits[ci, b]
// ctxT4 (D/4, B, 4)   : ctxT4[(d>>2)*256 + 4*b + (d&3)]  = context[b, d]
__global__ __launch_bounds__(256) void pack_pre(
    const float* __restrict__ logits,    // (C*I, B)
    const float* __restrict__ context,   // (B, D)
    float* __restrict__ Lt,
    float* __restrict__ Lpk,
    float* __restrict__ ctxT4)
{
    __shared__ float t[64][65];
    const int bid  = blockIdx.x;
    const int lane = threadIdx.x & 63;
    const int w    = threadIdx.x >> 6;
    if (bid < 64) {
        const int r0 = bid << 6;                     // ci base
        #pragma unroll
        for (int rep = 0; rep < 16; ++rep) {
            int rr = w * 16 + rep;
            t[rr][lane] = logits[(size_t)(r0 + rr) * 64 + lane];
        }
        __syncthreads();
        const int ci = r0 + lane;
        #pragma unroll
        for (int rep = 0; rep < 16; ++rep) {
            int b = w * 16 + rep;
            float v = t[lane][b];
            Lt[(size_t)b * 4096 + ci] = v;
            Lpk[(size_t)(ci >> 2) * 256 + 4 * b + (ci & 3)] = v;
        }
    } else {
        const int c0 = (bid - 64) << 6;              // d base
        #pragma unroll
        for (int rep = 0; rep < 16; ++rep) {
            int rr = w * 16 + rep;                   // b
            t[rr][lane] = context[(size_t)rr * 512 + c0 + lane];
        }
        __syncthreads();
        #pragma unroll
        for (int rep = 0; rep < 16; ++rep) {
            int dd = c0 + w * 16 + rep;              // d
            ctxT4[(size_t)(dd >> 2) * 256 + 4 * lane + (dd & 3)] = t[lane][w * 16 + rep];
        }
    }
}

__global__ __launch_bounds__(256, 8) void gln_fused(
    const float* __restrict__ target,   // (C, B)
    const float* __restrict__ cmaps,    // (C, S, 4, 512)
    const float* __restrict__ cbias,    // (C, S, 4, 1)
    const float* __restrict__ weights,  // (C, S, 16, 512)
    const float* __restrict__ Lt,
    const float* __restrict__ Lpk,
    const float* __restrict__ ctxT4,
    float* __restrict__ out,            // (C, S, B)
    float* __restrict__ outW)           // (C, S, 16, 512)
{
    __shared__ float Cm[CMS * CSZ];       // 8 KB cmaps slice
    __shared__ int   bits[CMS * BATCH];
    __shared__ float partial[4 * BATCH];
    __shared__ float diff_l[BATCH];
    __shared__ int   blast[NBUCKET];

    const int tid  = threadIdx.x;
    const int cs   = blockIdx.x;       // c*SIZE + s
    const int c    = cs >> 9;
    const int lane = tid & 63;
    const int wv   = tid >> 6;

    // 1) stage cmaps slice (4x512 f32) into LDS, coalesced
    {
        const float4* gcm = (const float4*)(cmaps + (size_t)cs * (CMS * CSZ));
        float4 a = gcm[tid];
        float4 b = gcm[tid + 256];
        ((float4*)Cm)[tid]       = a;
        ((float4*)Cm)[tid + 256] = b;
    }
    __syncthreads();

    // 2) phase 0: distance for k = wv, b = lane (coalesced float4 ctx loads)
    {
        const float4* ct4 = (const float4*)ctxT4 + lane;
        float acc = 0.f;
        #pragma unroll 4
        for (int d4 = 0; d4 < 128; ++d4) {
            float4 cm4 = *(const float4*)&Cm[wv * CSZ + d4 * 4];   // uniform LDS bcast
            float4 cv  = ct4[(size_t)d4 * 64];
            acc += cm4.x * cv.x + cm4.y * cv.y + cm4.z * cv.z + cm4.w * cv.w;
        }
        float bias = cbias[(size_t)cs * CMS + wv];
        bits[wv * BATCH + lane] = (acc > bias) ? 1 : 0;
    }
    __syncthreads();

    int idx_b = bits[lane] | (bits[BATCH + lane] << 1) |
                (bits[2 * BATCH + lane] << 2) | (bits[3 * BATCH + lane] << 3);

    // 3) phase 2: gather-dot straight from global (L1/L2 serve the 32 KB slice);
    //    wave wv covers i in [128*wv, 128*wv+128)
    const float* Wg = weights + (size_t)cs * (NBUCKET * ISZ);
    {
        const float4* Wrow = (const float4*)(Wg + (size_t)idx_b * ISZ) + wv * 32;
        const float4* Lp4  = (const float4*)Lpk + ((c * 128 + wv * 32) * 64 + lane);
        float acc = 0.f;
        #pragma unroll 4
        for (int d4 = 0; d4 < 32; ++d4) {
            float4 w4 = Wrow[d4];
            float4 l4 = Lp4[(size_t)d4 * 64];
            acc += w4.x * l4.x + w4.y * l4.y + w4.z * l4.z + w4.w * l4.w;
        }
        partial[wv * BATCH + lane] = acc;
    }
    __syncthreads();

    // 4) wave 0: out, diff, last-writer per bucket via ballot
    if (wv == 0) {
        float s = partial[lane] + partial[BATCH + lane] +
                  partial[2 * BATCH + lane] + partial[3 * BATCH + lane];
        const float hi = 4.595119850134589f;    // logit(0.99)
        float oc = fminf(fmaxf(s, -hi), hi);
        out[(size_t)cs * BATCH + lane] = oc;
        float sig = 1.f / (1.f + expf(-oc));
        diff_l[lane] = LR * (sig - target[c * BATCH + lane]);
        #pragma unroll
        for (int j = 0; j < NBUCKET; ++j) {
            unsigned long long m = __ballot(idx_b == j);
            if (lane == 0) blast[j] = m ? (63 - __clzll(m)) : -1;   // np last-write-wins
        }
    }
    __syncthreads();

    // 5) phase 3: per-bucket update using b_last only; stream W->outW coalesced
    float* gO = outW + (size_t)cs * (NBUCKET * ISZ);
    const float* LtC = Lt + (size_t)c * ISZ;    // + bl*4096 later
    #pragma unroll
    for (int it = 0; it < 8; ++it) {
        int f    = tid + it * 256;
        int row  = f >> 7;
        int col4 = f & 127;
        float4 w4 = ((const float4*)Wg)[f];      // linear re-read, L1/L2-hot
        int bl = blast[row];
        float4 r = w4;
        if (bl >= 0) {
            float coef = diff_l[bl];
            float4 l4  = ((const float4*)(LtC + (size_t)bl * 4096))[col4];
            r.x = fminf(fmaxf(w4.x - coef * l4.x, -WCLIP), WCLIP);
            r.y = fminf(fmaxf(w4.y - coef * l4.y, -WCLIP), WCLIP);
            r.z = fminf(fmaxf(w4.z - coef * l4.z, -WCLIP), WCLIP);
            r.w = fminf(fmaxf(w4.w - coef * l4.w, -WCLIP), WCLIP);
        }
        ((float4*)gO)[f] = r;
    }
}

extern "C" void kernel_launch(void* const* d_in, const int* in_sizes, int n_in,
                              void* d_out, int out_size, void* d_ws, size_t ws_size,
                              hipStream_t stream) {
    const float* logits  = (const float*)d_in[0];  // (8,512,64)
    const float* context = (const float*)d_in[1];  // (64,512)
    const float* target  = (const float*)d_in[2];  // (8,64)
    const float* cmaps   = (const float*)d_in[3];  // (8,512,4,512)
    const float* cbias   = (const float*)d_in[4];  // (8,512,4,1)
    const float* weights = (const float*)d_in[5];  // (8,512,16,512)

    float* out  = (float*)d_out;                        // (8,512,64)
    float* outW = out + (size_t)CLASSES * SIZE * BATCH; // (8,512,16,512)

    float* Lt    = (float*)d_ws;            // 1 MB
    float* Lpk   = Lt + 262144;             // 1 MB
    float* ctxT4 = Lpk + 262144;            // 128 KB

    pack_pre<<<72, 256, 0, stream>>>(logits, context, Lt, Lpk, ctxT4);
    gln_fused<<<CLASSES * SIZE, 256, 0, stream>>>(
        target, cmaps, cbias, weights, Lt, Lpk, ctxT4, out, outW);
}

// Round 4
// 158.505 us; speedup vs baseline: 1.1224x; 1.1224x over previous
//
#include <hip/hip_runtime.h>
#include <math.h>

#define CLASSES 8
#define SIZE 512
#define ISZ 512
#define CSZ 512
#define BATCH 64
#define CMS 4
#define NBUCKET 16
#define LR 0.01f
#define WCLIP 5.0f
#define WSTRIDE 516    // W gather: banks 4*(idx+off)%32 -> worst 2-way (free)
#define CMSTRIDE 516   // cmaps rows: 4 k-addresses land on 16 distinct banks

// ---------------- pre-pass: packed layouts in d_ws ----------------
// Lt    (B, C*I)      : Lt[b*4096 + ci]                  = logits[ci, b]
// Lpk   (C*I/4, B, 4) : Lpk[(ci>>2)*256 + 4*b + (ci&3)]  = logits[ci, b]
// ctxT4 (D/4, B, 4)   : ctxT4[(d>>2)*256 + 4*b + (d&3)]  = context[b, d]
__global__ __launch_bounds__(256) void pack_pre(
    const float* __restrict__ logits,    // (C*I, B)
    const float* __restrict__ context,   // (B, D)
    float* __restrict__ Lt,
    float* __restrict__ Lpk,
    float* __restrict__ ctxT4)
{
    __shared__ float t[64][65];
    const int bid  = blockIdx.x;
    const int lane = threadIdx.x & 63;
    const int w    = threadIdx.x >> 6;
    if (bid < 64) {
        const int r0 = bid << 6;                     // ci base
        #pragma unroll
        for (int rep = 0; rep < 16; ++rep) {
            int rr = w * 16 + rep;
            t[rr][lane] = logits[(size_t)(r0 + rr) * 64 + lane];
        }
        __syncthreads();
        const int ci = r0 + lane;
        #pragma unroll
        for (int rep = 0; rep < 16; ++rep) {
            int b = w * 16 + rep;
            float v = t[lane][b];
            Lt[(size_t)b * 4096 + ci] = v;
            Lpk[(size_t)(ci >> 2) * 256 + 4 * b + (ci & 3)] = v;
        }
    } else {
        const int c0 = (bid - 64) << 6;              // d base
        #pragma unroll
        for (int rep = 0; rep < 16; ++rep) {
            int rr = w * 16 + rep;                   // b
            t[rr][lane] = context[(size_t)rr * 512 + c0 + lane];
        }
        __syncthreads();
        #pragma unroll
        for (int rep = 0; rep < 16; ++rep) {
            int dd = c0 + w * 16 + rep;              // d
            ctxT4[(size_t)(dd >> 2) * 256 + 4 * lane + (dd & 3)] = t[lane][w * 16 + rep];
        }
    }
}

__global__ __launch_bounds__(256, 4) void gln_fused(
    const float* __restrict__ target,   // (C, B)
    const float* __restrict__ cmaps,    // (C, S, 4, 512)
    const float* __restrict__ cbias,    // (C, S, 4, 1)
    const float* __restrict__ weights,  // (C, S, 16, 512)
    const float* __restrict__ Lt,
    const float* __restrict__ Lpk,
    const float* __restrict__ ctxT4,
    float* __restrict__ out,            // (C, S, B)
    float* __restrict__ outW)           // (C, S, 16, 512)
{
    __shared__ float Wl[NBUCKET * WSTRIDE];   // 33 KB; front aliased as padded Cm (4x516)
    __shared__ int   bits[CMS * BATCH];
    __shared__ float partial[4 * BATCH];
    __shared__ float diff_l[BATCH];
    __shared__ int   blast[NBUCKET];

    const int tid  = threadIdx.x;
    const int cs   = blockIdx.x;       // c*SIZE + s
    const int c    = cs >> 9;
    const int lane = tid & 63;
    const int wv   = tid >> 6;

    // 1) stage cmaps slice (4x512) into padded rows of Wl-front, coalesced
    {
        const float4* gcm = (const float4*)(cmaps + (size_t)cs * (CMS * CSZ));
        float4 a = gcm[tid];
        float4 b = gcm[tid + 256];
        const int f0 = tid, f1 = tid + 256;
        *(float4*)&Wl[(f0 >> 7) * CMSTRIDE + (f0 & 127) * 4] = a;
        *(float4*)&Wl[(f1 >> 7) * CMSTRIDE + (f1 & 127) * 4] = b;
    }
    // 2) issue W-slice loads into registers; consumed after phase 0 (latency hidden)
    float4 wreg[8];
    {
        const float4* gW = (const float4*)(weights + (size_t)cs * (NBUCKET * ISZ));
        #pragma unroll
        for (int it = 0; it < 8; ++it) wreg[it] = gW[tid + it * 256];
    }
    __syncthreads();

    // 3) phase 0: lane = (k = lane&3, b = wv*16 + lane>>2).
    //    ctx: 16 b-float4s per wave -> 4 cache lines/instr, each wave reads only
    //    its own 16 batch columns (ctx L1 traffic 128 KB/block, compulsory).
    //    cmaps: 4 distinct LDS addresses, 16 distinct banks (CMSTRIDE pad).
    //    Summation order per (k,b) identical to prior rounds.
    {
        const int k = lane & 3;
        const int b = (wv << 4) | (lane >> 2);
        const float4* ct4 = (const float4*)ctxT4 + b;
        float acc = 0.f;
        #pragma unroll 4
        for (int d4 = 0; d4 < 128; ++d4) {
            float4 cm4 = *(const float4*)&Wl[k * CMSTRIDE + d4 * 4];
            float4 cv  = ct4[(size_t)d4 * 64];
            acc += cm4.x * cv.x + cm4.y * cv.y + cm4.z * cv.z + cm4.w * cv.w;
        }
        float bias = cbias[(size_t)cs * CMS + k];
        bits[k * BATCH + b] = (acc > bias) ? 1 : 0;
    }
    __syncthreads();

    // 4) overwrite Wl with weight rows (padded stride); bucket idx per lane
    #pragma unroll
    for (int it = 0; it < 8; ++it) {
        int f = tid + it * 256;
        *(float4*)&Wl[(f >> 7) * WSTRIDE + (f & 127) * 4] = wreg[it];
    }
    int idx_b = bits[lane] | (bits[BATCH + lane] << 1) |
                (bits[2 * BATCH + lane] << 2) | (bits[3 * BATCH + lane] << 3);
    __syncthreads();

    // 5) phase 2: gather-dot from LDS; wave wv covers i in [128*wv, 128*wv+128)
    {
        const float4* Lp4 = (const float4*)Lpk;
        const int base4 = (c * 128 + wv * 32) * 64 + lane;
        const int wb    = idx_b * WSTRIDE + wv * 128;
        float acc = 0.f;
        #pragma unroll 4
        for (int d4 = 0; d4 < 32; ++d4) {
            float4 w4 = *(const float4*)&Wl[wb + d4 * 4];
            float4 l4 = Lp4[(size_t)base4 + d4 * 64];
            acc += w4.x * l4.x + w4.y * l4.y + w4.z * l4.z + w4.w * l4.w;
        }
        partial[wv * BATCH + lane] = acc;
    }
    __syncthreads();

    // 6) wave 0: out, diff, last-writer per bucket via ballot
    if (wv == 0) {
        float s = partial[lane] + partial[BATCH + lane] +
                  partial[2 * BATCH + lane] + partial[3 * BATCH + lane];
        const float hi = 4.595119850134589f;    // logit(0.99)
        float oc = fminf(fmaxf(s, -hi), hi);
        out[(size_t)cs * BATCH + lane] = oc;
        float sig = 1.f / (1.f + expf(-oc));
        diff_l[lane] = LR * (sig - target[c * BATCH + lane]);
        #pragma unroll
        for (int j = 0; j < NBUCKET; ++j) {
            unsigned long long m = __ballot(idx_b == j);
            if (lane == 0) blast[j] = m ? (63 - __clzll(m)) : -1;   // np last-write-wins
        }
    }
    __syncthreads();

    // 7) phase 3: per-bucket update using b_last only; stream out coalesced
    float* gO = outW + (size_t)cs * (NBUCKET * ISZ);
    const float* LtC = Lt + (size_t)c * ISZ;    // + bl*4096 later
    #pragma unroll
    for (int it = 0; it < 8; ++it) {
        int f    = tid + it * 256;
        int row  = f >> 7;
        int col4 = f & 127;
        float4 w4 = *(const float4*)&Wl[row * WSTRIDE + col4 * 4];
        int bl = blast[row];
        float4 r = w4;
        if (bl >= 0) {
            float coef = diff_l[bl];
            float4 l4  = ((const float4*)(LtC + (size_t)bl * 4096))[col4];
            r.x = fminf(fmaxf(w4.x - coef * l4.x, -WCLIP), WCLIP);
            r.y = fminf(fmaxf(w4.y - coef * l4.y, -WCLIP), WCLIP);
            r.z = fminf(fmaxf(w4.z - coef * l4.z, -WCLIP), WCLIP);
            r.w = fminf(fmaxf(w4.w - coef * l4.w, -WCLIP), WCLIP);
        }
        ((float4*)gO)[f] = r;
    }
}

extern "C" void kernel_launch(void* const* d_in, const int* in_sizes, int n_in,
                              void* d_out, int out_size, void* d_ws, size_t ws_size,
                              hipStream_t stream) {
    const float* logits  = (const float*)d_in[0];  // (8,512,64)
    const float* context = (const float*)d_in[1];  // (64,512)
    const float* target  = (const float*)d_in[2];  // (8,64)
    const float* cmaps   = (const float*)d_in[3];  // (8,512,4,512)
    const float* cbias   = (const float*)d_in[4];  // (8,512,4,1)
    const float* weights = (const float*)d_in[5];  // (8,512,16,512)

    float* out  = (float*)d_out;                        // (8,512,64)
    float* outW = out + (size_t)CLASSES * SIZE * BATCH; // (8,512,16,512)

    float* Lt    = (float*)d_ws;            // 1 MB
    float* Lpk   = Lt + 262144;             // 1 MB
    float* ctxT4 = Lpk + 262144;            // 128 KB

    pack_pre<<<72, 256, 0, stream>>>(logits, context, Lt, Lpk, ctxT4);
    gln_fused<<<CLASSES * SIZE, 256, 0, stream>>>(
        target, cmaps, cbias, weights, Lt, Lpk, ctxT4, out, outW);
}

// Round 7
// 144.335 us; speedup vs baseline: 1.2326x; 1.0982x over previous
//
#include <hip/hip_runtime.h>
#include <math.h>

#define CLASSES 8
#define SIZE 512
#define ISZ 512
#define CSZ 512
#define BATCH 64
#define CMS 4
#define NBUCKET 16
#define LR 0.01f
#define WCLIP 5.0f
#define WSTRIDE 516    // W gather: banks 4*(idx+off)%32 -> worst 2-way (free)
#define CMSTRIDE 516   // cmaps rows: 4 k-addresses land on 16 distinct banks

// ---------------- kernel 1: pack (R4 verbatim) ----------------
// Lt    (B, C*I)      : Lt[b*4096 + ci]                  = logits[ci, b]
// Lpk   (C*I/4, B, 4) : Lpk[(ci>>2)*256 + 4*b + (ci&3)]  = logits[ci, b]
// ctxT4 (D/4, B, 4)   : ctxT4[(d>>2)*256 + 4*b + (d&3)]  = context[b, d]
__global__ __launch_bounds__(256) void pack_pre(
    const float* __restrict__ logits,    // (C*I, B)
    const float* __restrict__ context,   // (B, D)
    float* __restrict__ Lt,
    float* __restrict__ Lpk,
    float* __restrict__ ctxT4)
{
    __shared__ float t[64][65];
    const int bid  = blockIdx.x;
    const int lane = threadIdx.x & 63;
    const int w    = threadIdx.x >> 6;
    if (bid < 64) {
        const int r0 = bid << 6;                     // ci base
        #pragma unroll
        for (int rep = 0; rep < 16; ++rep) {
            int rr = w * 16 + rep;
            t[rr][lane] = logits[(size_t)(r0 + rr) * 64 + lane];
        }
        __syncthreads();
        const int ci = r0 + lane;
        #pragma unroll
        for (int rep = 0; rep < 16; ++rep) {
            int b = w * 16 + rep;
            float v = t[lane][b];
            Lt[(size_t)b * 4096 + ci] = v;
            Lpk[(size_t)(ci >> 2) * 256 + 4 * b + (ci & 3)] = v;
        }
    } else {
        const int c0 = (bid - 64) << 6;              // d base
        #pragma unroll
        for (int rep = 0; rep < 16; ++rep) {
            int rr = w * 16 + rep;                   // b
            t[rr][lane] = context[(size_t)rr * 512 + c0 + lane];
        }
        __syncthreads();
        #pragma unroll
        for (int rep = 0; rep < 16; ++rep) {
            int dd = c0 + w * 16 + rep;              // d
            ctxT4[(size_t)(dd >> 2) * 256 + 4 * lane + (dd & 3)] = t[lane][w * 16 + rep];
        }
    }
}

// ---------------- kernel 2: distances -> bucket idx ----------------
// CHARACTER-LEVEL copy of R4's passing phase 0 (staging + mapping + expression).
// Do NOT re-derive this loop: the bucket comparison sits on FP knife edges and
// this exact codegen is the proven-matching one (R5/R6 post-mortem).
__global__ __launch_bounds__(256, 4) void dist_kernel(
    const float* __restrict__ cmaps,     // (C, S, 4, 512)
    const float* __restrict__ cbias,     // (C, S, 4, 1)
    const float* __restrict__ ctxT4,     // packed context
    unsigned char* __restrict__ idxOut)  // (4096, 64)
{
    __shared__ float Wl[4 * CMSTRIDE];   // cmaps rows, padded (8.1 KB)
    __shared__ int   bits[CMS * BATCH];

    const int tid  = threadIdx.x;
    const int cs   = blockIdx.x;       // c*SIZE + s
    const int lane = tid & 63;
    const int wv   = tid >> 6;

    // 1) stage cmaps slice (4x512) into padded rows, coalesced (R4 verbatim)
    {
        const float4* gcm = (const float4*)(cmaps + (size_t)cs * (CMS * CSZ));
        float4 a = gcm[tid];
        float4 b = gcm[tid + 256];
        const int f0 = tid, f1 = tid + 256;
        *(float4*)&Wl[(f0 >> 7) * CMSTRIDE + (f0 & 127) * 4] = a;
        *(float4*)&Wl[(f1 >> 7) * CMSTRIDE + (f1 & 127) * 4] = b;
    }
    __syncthreads();

    // 2) phase 0: lane = (k = lane&3, b = wv*16 + lane>>2)  (R4 verbatim)
    {
        const int k = lane & 3;
        const int b = (wv << 4) | (lane >> 2);
        const float4* ct4 = (const float4*)ctxT4 + b;
        float acc = 0.f;
        #pragma unroll 4
        for (int d4 = 0; d4 < 128; ++d4) {
            float4 cm4 = *(const float4*)&Wl[k * CMSTRIDE + d4 * 4];
            float4 cv  = ct4[(size_t)d4 * 64];
            acc += cm4.x * cv.x + cm4.y * cv.y + cm4.z * cv.z + cm4.w * cv.w;
        }
        float bias = cbias[(size_t)cs * CMS + k];
        bits[k * BATCH + b] = (acc > bias) ? 1 : 0;
    }
    __syncthreads();

    // 3) wave 0 emits idx bytes (same combine expression as R4)
    if (wv == 0) {
        int idx_b = bits[lane] | (bits[BATCH + lane] << 1) |
                    (bits[2 * BATCH + lane] << 2) | (bits[3 * BATCH + lane] << 3);
        idxOut[(size_t)cs * BATCH + lane] = (unsigned char)idx_b;
    }
}

// ---------------- kernel 3: gather-dot + update (R4 phases 1-3) ----------------
__global__ __launch_bounds__(256, 4) void gln_bc(
    const float* __restrict__ target,   // (C, B)
    const float* __restrict__ weights,  // (C, S, 16, 512)
    const unsigned char* __restrict__ idxIn,
    const float* __restrict__ Lt,
    const float* __restrict__ Lpk,
    float* __restrict__ out,            // (C, S, B)
    float* __restrict__ outW)           // (C, S, 16, 512)
{
    __shared__ float Wl[NBUCKET * WSTRIDE];   // 33 KB padded rows
    __shared__ float partial[4 * BATCH];
    __shared__ float diff_l[BATCH];
    __shared__ int   blast[NBUCKET];

    const int tid  = threadIdx.x;
    const int cs   = blockIdx.x;
    const int c    = cs >> 9;
    const int lane = tid & 63;
    const int wv   = tid >> 6;

    // stage W slice (16 x 512 f32) into padded LDS
    float4 wreg[8];
    const float4* gW = (const float4*)(weights + (size_t)cs * (NBUCKET * ISZ));
    #pragma unroll
    for (int it = 0; it < 8; ++it) wreg[it] = gW[tid + it * 256];

    const int idx_b = idxIn[(size_t)cs * BATCH + lane];

    #pragma unroll
    for (int it = 0; it < 8; ++it) {
        int f = tid + it * 256;
        *(float4*)&Wl[(f >> 7) * WSTRIDE + (f & 127) * 4] = wreg[it];
    }
    __syncthreads();

    // gather-dot: wave wv covers i in [128*wv, 128*wv+128)
    {
        const float4* Lp4 = (const float4*)Lpk;
        const int base4 = (c * 128 + wv * 32) * 64 + lane;
        const int wb    = idx_b * WSTRIDE + wv * 128;
        float acc = 0.f;
        #pragma unroll 4
        for (int d4 = 0; d4 < 32; ++d4) {
            float4 w4 = *(const float4*)&Wl[wb + d4 * 4];
            float4 l4 = Lp4[(size_t)base4 + d4 * 64];
            acc += w4.x * l4.x + w4.y * l4.y + w4.z * l4.z + w4.w * l4.w;
        }
        partial[wv * BATCH + lane] = acc;
    }
    __syncthreads();

    // wave 0: out, diff, last-writer per bucket via ballot
    if (wv == 0) {
        float s = partial[lane] + partial[BATCH + lane] +
                  partial[2 * BATCH + lane] + partial[3 * BATCH + lane];
        const float hi = 4.595119850134589f;    // logit(0.99)
        float oc = fminf(fmaxf(s, -hi), hi);
        out[(size_t)cs * BATCH + lane] = oc;
        float sig = 1.f / (1.f + expf(-oc));
        diff_l[lane] = LR * (sig - target[c * BATCH + lane]);
        #pragma unroll
        for (int j = 0; j < NBUCKET; ++j) {
            unsigned long long m = __ballot(idx_b == j);
            if (lane == 0) blast[j] = m ? (63 - __clzll(m)) : -1;   // np last-write-wins
        }
    }
    __syncthreads();

    // per-bucket update using b_last only; stream out coalesced
    float* gO = outW + (size_t)cs * (NBUCKET * ISZ);
    const float* LtC = Lt + (size_t)c * ISZ;
    #pragma unroll
    for (int it = 0; it < 8; ++it) {
        int f    = tid + it * 256;
        int row  = f >> 7;
        int col4 = f & 127;
        float4 w4 = *(const float4*)&Wl[row * WSTRIDE + col4 * 4];
        int bl = blast[row];
        float4 r = w4;
        if (bl >= 0) {
            float coef = diff_l[bl];
            float4 l4  = ((const float4*)(LtC + (size_t)bl * 4096))[col4];
            r.x = fminf(fmaxf(w4.x - coef * l4.x, -WCLIP), WCLIP);
            r.y = fminf(fmaxf(w4.y - coef * l4.y, -WCLIP), WCLIP);
            r.z = fminf(fmaxf(w4.z - coef * l4.z, -WCLIP), WCLIP);
            r.w = fminf(fmaxf(w4.w - coef * l4.w, -WCLIP), WCLIP);
        }
        ((float4*)gO)[f] = r;
    }
}

extern "C" void kernel_launch(void* const* d_in, const int* in_sizes, int n_in,
                              void* d_out, int out_size, void* d_ws, size_t ws_size,
                              hipStream_t stream) {
    const float* logits  = (const float*)d_in[0];  // (8,512,64)
    const float* context = (const float*)d_in[1];  // (64,512)
    const float* target  = (const float*)d_in[2];  // (8,64)
    const float* cmaps   = (const float*)d_in[3];  // (8,512,4,512)
    const float* cbias   = (const float*)d_in[4];  // (8,512,4,1)
    const float* weights = (const float*)d_in[5];  // (8,512,16,512)

    float* out  = (float*)d_out;                        // (8,512,64)
    float* outW = out + (size_t)CLASSES * SIZE * BATCH; // (8,512,16,512)

    float* Lt    = (float*)d_ws;            // 1 MB
    float* Lpk   = Lt + 262144;             // 1 MB
    float* ctxT4 = Lpk + 262144;            // 128 KB
    unsigned char* idxb = (unsigned char*)(ctxT4 + 32768);   // 256 KB

    pack_pre<<<72, 256, 0, stream>>>(logits, context, Lt, Lpk, ctxT4);
    dist_kernel<<<CLASSES * SIZE, 256, 0, stream>>>(cmaps, cbias, ctxT4, idxb);
    gln_bc<<<CLASSES * SIZE, 256, 0, stream>>>(target, weights, idxb, Lt, Lpk, out, outW);
}

// Round 8
// 140.842 us; speedup vs baseline: 1.2632x; 1.0248x over previous
//
#include <hip/hip_runtime.h>
#include <math.h>

#define CLASSES 8
#define SIZE 512
#define ISZ 512
#define CSZ 512
#define BATCH 64
#define CMS 4
#define NBUCKET 16
#define LR 0.01f
#define WCLIP 5.0f
#define WSTRIDE 516    // W gather: banks 4*(idx+off)%32 -> worst 2-way (free)

// ---------------- kernel 1: pack (R4 verbatim) ----------------
// Lt    (B, C*I)      : Lt[b*4096 + ci]                  = logits[ci, b]
// Lpk   (C*I/4, B, 4) : Lpk[(ci>>2)*256 + 4*b + (ci&3)]  = logits[ci, b]
// ctxT4 (D/4, B, 4)   : ctxT4[(d>>2)*256 + 4*b + (d&3)]  = context[b, d]
__global__ __launch_bounds__(256) void pack_pre(
    const float* __restrict__ logits,    // (C*I, B)
    const float* __restrict__ context,   // (B, D)
    float* __restrict__ Lt,
    float* __restrict__ Lpk,
    float* __restrict__ ctxT4)
{
    __shared__ float t[64][65];
    const int bid  = blockIdx.x;
    const int lane = threadIdx.x & 63;
    const int w    = threadIdx.x >> 6;
    if (bid < 64) {
        const int r0 = bid << 6;                     // ci base
        #pragma unroll
        for (int rep = 0; rep < 16; ++rep) {
            int rr = w * 16 + rep;
            t[rr][lane] = logits[(size_t)(r0 + rr) * 64 + lane];
        }
        __syncthreads();
        const int ci = r0 + lane;
        #pragma unroll
        for (int rep = 0; rep < 16; ++rep) {
            int b = w * 16 + rep;
            float v = t[lane][b];
            Lt[(size_t)b * 4096 + ci] = v;
            Lpk[(size_t)(ci >> 2) * 256 + 4 * b + (ci & 3)] = v;
        }
    } else {
        const int c0 = (bid - 64) << 6;              // d base
        #pragma unroll
        for (int rep = 0; rep < 16; ++rep) {
            int rr = w * 16 + rep;                   // b
            t[rr][lane] = context[(size_t)rr * 512 + c0 + lane];
        }
        __syncthreads();
        #pragma unroll
        for (int rep = 0; rep < 16; ++rep) {
            int dd = c0 + w * 16 + rep;              // d
            ctxT4[(size_t)(dd >> 2) * 256 + 4 * lane + (dd & 3)] = t[lane][w * 16 + rep];
        }
    }
}

// ---------------- kernel 2: distances -> bucket idx ----------------
// R1's passing layout (wave = k, lane = b) and R2's passing phase-0 expression
// VERBATIM (single-acc 4-term chain, #pragma unroll 4). Only the cm4 operand
// source changes: wave-uniform GLOBAL pointer (readfirstlane-forced) -> s_load
// through the scalar cache, zero LDS traffic in the inner loop.
// Do NOT re-derive this loop (R5/R6 knife-edge post-mortem).
__global__ __launch_bounds__(256, 8) void dist_kernel(
    const float* __restrict__ cmaps,     // (C, S, 4, 512)
    const float* __restrict__ cbias,     // (C, S, 4, 1)
    const float* __restrict__ ctxT4,     // packed context
    unsigned char* __restrict__ idxOut)  // (4096, 64)
{
    __shared__ int bits[CMS * BATCH];

    const int tid  = threadIdx.x;
    const int cs   = blockIdx.x;       // c*SIZE + s
    const int lane = tid & 63;
    const int wv   = tid >> 6;
    const int k    = __builtin_amdgcn_readfirstlane(wv);   // wave-uniform

    const float4* cmg = (const float4*)(cmaps + ((size_t)cs * CMS + k) * CSZ);
    {
        const float4* ct4 = (const float4*)ctxT4 + lane;
        float acc = 0.f;
        #pragma unroll 4
        for (int d4 = 0; d4 < 128; ++d4) {
            float4 cm4 = cmg[d4];                    // uniform -> s_load_dwordx4
            float4 cv  = ct4[(size_t)d4 * 64];
            acc += cm4.x * cv.x + cm4.y * cv.y + cm4.z * cv.z + cm4.w * cv.w;
        }
        float bias = cbias[(size_t)cs * CMS + k];
        bits[k * BATCH + lane] = (acc > bias) ? 1 : 0;
    }
    __syncthreads();

    if (wv == 0) {
        int idx_b = bits[lane] | (bits[BATCH + lane] << 1) |
                    (bits[2 * BATCH + lane] << 2) | (bits[3 * BATCH + lane] << 3);
        idxOut[(size_t)cs * BATCH + lane] = (unsigned char)idx_b;
    }
}

// ---------------- kernel 3: gather-dot + update ----------------
__global__ __launch_bounds__(256, 4) void gln_bc(
    const float* __restrict__ target,   // (C, B)
    const float* __restrict__ weights,  // (C, S, 16, 512)
    const unsigned char* __restrict__ idxIn,
    const float* __restrict__ Lt,
    const float* __restrict__ Lpk,
    float* __restrict__ out,            // (C, S, B)
    float* __restrict__ outW)           // (C, S, 16, 512)
{
    __shared__ float Wl[NBUCKET * WSTRIDE];   // 33 KB padded rows
    __shared__ float partial[4 * BATCH];
    __shared__ float diff_l[BATCH];
    __shared__ int   blast[NBUCKET];

    const int tid  = threadIdx.x;
    const int cs   = blockIdx.x;
    const int c    = cs >> 9;
    const int lane = tid & 63;
    const int wv   = tid >> 6;

    // stage W slice (16 x 512 f32): global -> regs -> padded LDS
    float4 wreg[8];
    const float4* gW = (const float4*)(weights + (size_t)cs * (NBUCKET * ISZ));
    #pragma unroll
    for (int it = 0; it < 8; ++it) wreg[it] = gW[tid + it * 256];

    const int idx_b = idxIn[(size_t)cs * BATCH + lane];

    // last-writer per bucket: wave wv owns buckets wv*4..wv*4+3; hoisted off
    // the critical tail (depends only on idx). np last-write-wins semantics.
    #pragma unroll
    for (int jj = 0; jj < 4; ++jj) {
        int j = (wv << 2) + jj;
        unsigned long long m = __ballot(idx_b == j);
        if (lane == 0) blast[j] = m ? (63 - __clzll(m)) : -1;
    }

    #pragma unroll
    for (int it = 0; it < 8; ++it) {
        int f = tid + it * 256;
        *(float4*)&Wl[(f >> 7) * WSTRIDE + (f & 127) * 4] = wreg[it];
    }
    __syncthreads();

    // gather-dot: wave wv covers i in [128*wv, 128*wv+128)
    {
        const float4* Lp4 = (const float4*)Lpk;
        const int base4 = (c * 128 + wv * 32) * 64 + lane;
        const int wb    = idx_b * WSTRIDE + wv * 128;
        float acc = 0.f;
        #pragma unroll 4
        for (int d4 = 0; d4 < 32; ++d4) {
            float4 w4 = *(const float4*)&Wl[wb + d4 * 4];
            float4 l4 = Lp4[(size_t)base4 + d4 * 64];
            acc += w4.x * l4.x + w4.y * l4.y + w4.z * l4.z + w4.w * l4.w;
        }
        partial[wv * BATCH + lane] = acc;
    }
    __syncthreads();

    // wave 0: out + diff only (ballots already done)
    if (wv == 0) {
        float s = partial[lane] + partial[BATCH + lane] +
                  partial[2 * BATCH + lane] + partial[3 * BATCH + lane];
        const float hi = 4.595119850134589f;    // logit(0.99)
        float oc = fminf(fmaxf(s, -hi), hi);
        out[(size_t)cs * BATCH + lane] = oc;
        float sig = 1.f / (1.f + expf(-oc));
        diff_l[lane] = LR * (sig - target[c * BATCH + lane]);
    }
    __syncthreads();

    // per-bucket update from wreg (no LDS re-read); stream out coalesced
    float* gO = outW + (size_t)cs * (NBUCKET * ISZ);
    const float* LtC = Lt + (size_t)c * ISZ;
    #pragma unroll
    for (int it = 0; it < 8; ++it) {
        int f    = tid + it * 256;
        int row  = f >> 7;
        int col4 = f & 127;
        float4 w4 = wreg[it];
        int bl = blast[row];
        float4 r = w4;
        if (bl >= 0) {
            float coef = diff_l[bl];
            float4 l4  = ((const float4*)(LtC + (size_t)bl * 4096))[col4];
            r.x = fminf(fmaxf(w4.x - coef * l4.x, -WCLIP), WCLIP);
            r.y = fminf(fmaxf(w4.y - coef * l4.y, -WCLIP), WCLIP);
            r.z = fminf(fmaxf(w4.z - coef * l4.z, -WCLIP), WCLIP);
            r.w = fminf(fmaxf(w4.w - coef * l4.w, -WCLIP), WCLIP);
        }
        ((float4*)gO)[f] = r;
    }
}

extern "C" void kernel_launch(void* const* d_in, const int* in_sizes, int n_in,
                              void* d_out, int out_size, void* d_ws, size_t ws_size,
                              hipStream_t stream) {
    const float* logits  = (const float*)d_in[0];  // (8,512,64)
    const float* context = (const float*)d_in[1];  // (64,512)
    const float* target  = (const float*)d_in[2];  // (8,64)
    const float* cmaps   = (const float*)d_in[3];  // (8,512,4,512)
    const float* cbias   = (const float*)d_in[4];  // (8,512,4,1)
    const float* weights = (const float*)d_in[5];  // (8,512,16,512)

    float* out  = (float*)d_out;                        // (8,512,64)
    float* outW = out + (size_t)CLASSES * SIZE * BATCH; // (8,512,16,512)

    float* Lt    = (float*)d_ws;            // 1 MB
    float* Lpk   = Lt + 262144;             // 1 MB
    float* ctxT4 = Lpk + 262144;            // 128 KB
    unsigned char* idxb = (unsigned char*)(ctxT4 + 32768);   // 256 KB

    pack_pre<<<72, 256, 0, stream>>>(logits, context, Lt, Lpk, ctxT4);
    dist_kernel<<<CLASSES * SIZE, 256, 0, stream>>>(cmaps, cbias, ctxT4, idxb);
    gln_bc<<<CLASSES * SIZE, 256, 0, stream>>>(target, weights, idxb, Lt, Lpk, out, outW);
}